// Round 5
// baseline (329.705 us; speedup 1.0000x reference)
//
#include <hip/hip_runtime.h>
#include <hip/hip_bf16.h>
#include <math.h>

// Problem constants
#define BB 32
#define LL 4100
#define SS 1024
#define EE 16
#define HH 4
#define DHD 4
#define NCC 10

// Workspace layout (in floats)
#define OFF_PE   0                       // S*E = 16384
#define OFF_H1   16384                   // B*8*S = 262144
#define OFF_H2   (OFF_H1 + 262144)       // B*32*S = 1048576
#define OFF_XSRC (OFF_H2 + 1048576)      // B*S*E = 524288
#define OFF_Q    (OFF_XSRC + 524288)     // B*H*S*DH = 524288 (also gdw temp before qkv)
#define OFF_K    (OFF_Q + 524288)
#define OFF_V    (OFF_K + 524288)
#define OFF_Z    (OFF_V + 524288)        // layer-1 output
#define OFF_END  (OFF_Z + 524288)        // 3,948,544 floats = 15.8 MB
#define OFF_Z2   OFF_XSRC                // reuse xsrc for final z2 (xsrc dead after post1)

__global__ __launch_bounds__(256) void pe_kernel(float* pe) {
    int idx = blockIdx.x * 256 + threadIdx.x;       // S*E = 16384
    int s = idx >> 4, e = idx & 15;
    int j = e >> 1;
    float div = exp2f((float)j * -1.66096404744f);  // 10000^(-j/8)
    float ang = (float)s * div * (16.f / 1024.f);
    pe[idx] = (e & 1) ? cosf(ang) : sinf(ang);
}

__global__ __launch_bounds__(256) void conv1_kernel(const float* __restrict__ x,
        const float* __restrict__ w, const float* __restrict__ bias,
        const float* __restrict__ g, const float* __restrict__ bb,
        float* __restrict__ h1) {
    int idx = blockIdx.x * 256 + threadIdx.x;       // B*8*S
    int s = idx & 1023; int c = (idx >> 10) & 7; int b = idx >> 13;
    const float* xp = x + b * LL + 4 * s;
    float acc = bias[c];
    #pragma unroll
    for (int k = 0; k < 8; k++) acc += xp[k] * w[c * 8 + k];
    float inv = rsqrtf(1.f + 1e-5f);
    float v = acc * inv * g[c] + bb[c];
    h1[idx] = fmaxf(v, 0.f);
}

__global__ __launch_bounds__(256) void conv2_kernel(const float* __restrict__ h1,
        const float* __restrict__ w, const float* __restrict__ bias,
        const float* __restrict__ g, const float* __restrict__ bb,
        float* __restrict__ h2) {
    int s = blockIdx.x * 256 + threadIdx.x;
    int o = blockIdx.y, b = blockIdx.z;
    const float* hp = h1 + b * 8 * SS;
    float acc = bias[o];
    #pragma unroll
    for (int i = 0; i < 8; i++) {
        const float* row = hp + i * SS;
        const float* wr = w + (o * 8 + i) * 8;
        #pragma unroll
        for (int k = 0; k < 8; k++) {
            int t = s - 3 + k;
            if (t >= 0 && t < SS) acc += row[t] * wr[k];
        }
    }
    float inv = rsqrtf(1.f + 1e-5f);
    float v = acc * inv * g[o] + bb[o];
    h2[(b * 32 + o) * SS + s] = fmaxf(v, 0.f);
}

// Depthwise grouped conv (32->16, k=32, groups=16): thread = (b, o, s).
__global__ __launch_bounds__(256) void dw_kernel(const float* __restrict__ h2,
        const float* __restrict__ dw, float* __restrict__ gdw) {
    int s = blockIdx.x * 256 + threadIdx.x;
    int o = blockIdx.y, b = blockIdx.z;
    const float* r0 = h2 + (size_t)(b * 32 + 2 * o) * SS;
    const float* r1 = r0 + SS;
    const float* w0 = dw + (o * 2) * 32;   // uniform -> scalar loads
    const float* w1 = w0 + 32;
    float acc = 0.f;
    #pragma unroll
    for (int kk = 0; kk < 32; kk++) {
        int t = s - 15 + kk;
        if (t >= 0 && t < SS) acc += r0[t] * w0[kk] + r1[t] * w1[kk];
    }
    gdw[(size_t)(b * 16 + o) * SS + s] = acc;
}

// Pointwise 1x1 conv (16->16) + BN + ReLU, output pre-transposed [B,S,16]
__global__ __launch_bounds__(64) void pw_kernel(const float* __restrict__ gdw,
        const float* __restrict__ pw, const float* __restrict__ g,
        const float* __restrict__ bb, float* __restrict__ xsrc) {
    __shared__ float spw[256];
    int tid = threadIdx.x;
    for (int i = tid; i < 256; i += 64) spw[i] = pw[i];
    __syncthreads();
    int idx = blockIdx.x * 64 + tid;                // b*S + s
    int s = idx & 1023, b = idx >> 10;
    float gout[16];
    #pragma unroll
    for (int o = 0; o < 16; o++) gout[o] = gdw[(size_t)(b * 16 + o) * SS + s];
    float inv = rsqrtf(1.f + 1e-5f);
    float* xp = xsrc + (size_t)idx * 16;
    #pragma unroll
    for (int p = 0; p < 16; p++) {
        float acc = 0.f;
        #pragma unroll
        for (int o = 0; o < 16; o++) acc += spw[p * 16 + o] * gout[o];
        float v = acc * inv * g[p] + bb[p];
        xp[p] = fmaxf(v, 0.f);
    }
}

// QKV projection, split 3-way by blockIdx.y (0=Q,1=K,2=V).
// t = xin[b,s,:] + pe[s,:];  out[e] = sum_f W[e,f]*t[f]
// Output layout: [B,H,S,DH] for contiguous float4 reads in attention.
__global__ __launch_bounds__(64) void qkv_kernel(const float* __restrict__ xin,
        const float* __restrict__ pe,
        const float* __restrict__ wq, const float* __restrict__ wk,
        const float* __restrict__ wv,
        float* __restrict__ q, float* __restrict__ k, float* __restrict__ v) {
    __shared__ float sw[256];
    int tid = threadIdx.x;
    int which = blockIdx.y;
    const float* wsel = (which == 0) ? wq : (which == 1) ? wk : wv;
    float* osel = (which == 0) ? q : (which == 1) ? k : v;
    for (int i = tid; i < 256; i += 64) sw[i] = wsel[i];
    __syncthreads();
    int idx = blockIdx.x * 64 + tid;                // b*S + s
    int s = idx & 1023; int b = idx >> 10;
    float t[16];
    const float4* xp4 = (const float4*)(xin + (size_t)idx * 16);
    const float4* pp4 = (const float4*)(pe + s * 16);
    #pragma unroll
    for (int i = 0; i < 4; i++) {
        float4 a = xp4[i], p = pp4[i];
        t[4*i+0] = a.x + p.x; t[4*i+1] = a.y + p.y;
        t[4*i+2] = a.z + p.z; t[4*i+3] = a.w + p.w;
    }
    #pragma unroll
    for (int e = 0; e < 16; e++) {
        float acc = 0.f;
        #pragma unroll
        for (int f = 0; f < 16; f++) acc += sw[e * 16 + f] * t[f];
        int h = e >> 2, d = e & 3;
        osel[((size_t)(b * HH + h) * SS + s) * DHD + d] = acc;
    }
}

// Attention core, single-pass no-max softmax with t-split + 4-way query tiling.
// Each thread handles queries {tid, tid+256, tid+512, tid+768}, so each K[t]/V[t]
// LDS read is amortized over 4 scores (Round-4 showed the broadcast ds_read
// bandwidth, not VALU issue, was the wall).
// Scores sc = (q.k)*scale*|t-s|/n are O(1) -> exp without max is exact and safe.
template <int TCHUNK>
__global__ __launch_bounds__(256) void attn_kernel(const float* __restrict__ q,
        const float* __restrict__ k, const float* __restrict__ v,
        float* __restrict__ partO, float* __restrict__ partL) {
    __shared__ float4 Ks[TCHUNK], Vs[TCHUNK];
    int bh = blockIdx.x;                             // b*H + h
    int tc = blockIdx.y;
    int tid = threadIdx.x;
    int t0 = tc * TCHUNK;
    const float4* kp = (const float4*)(k + (size_t)bh * SS * DHD) + t0;
    const float4* vp = (const float4*)(v + (size_t)bh * SS * DHD) + t0;
    for (int t = tid; t < TCHUNK; t += 256) { Ks[t] = kp[t]; Vs[t] = vp[t]; }
    __syncthreads();
    const float4* qp = (const float4*)(q + (size_t)bh * SS * DHD);
    // fold scale * 1/n * log2(e) into q so inner loop is: p = exp2((q.k) * |t-s|)
    const float cs = (0.25f / 1024.f) * 1.44269504089f;
    float4 qv[4];
    float tf[4], l[4];
    float4 oacc[4];
    #pragma unroll
    for (int i = 0; i < 4; i++) {
        int s = tid + 256 * i;
        float4 qq = qp[s];
        qv[i] = make_float4(qq.x * cs, qq.y * cs, qq.z * cs, qq.w * cs);
        tf[i] = (float)(t0 - s);
        l[i] = 0.f;
        oacc[i] = make_float4(0.f, 0.f, 0.f, 0.f);
    }
    for (int t = 0; t < TCHUNK; t++) {
        float4 kk = Ks[t];
        float4 vv = Vs[t];
        #pragma unroll
        for (int i = 0; i < 4; i++) {
            float d = qv[i].x*kk.x + qv[i].y*kk.y + qv[i].z*kk.z + qv[i].w*kk.w;
            float p = exp2f(d * fabsf(tf[i]));
            tf[i] += 1.f;
            l[i] += p;
            oacc[i].x += p*vv.x; oacc[i].y += p*vv.y;
            oacc[i].z += p*vv.z; oacc[i].w += p*vv.w;
        }
    }
    #pragma unroll
    for (int i = 0; i < 4; i++) {
        int s = tid + 256 * i;
        size_t o = (size_t)(tc * (BB * HH) + bh) * SS + s;
        ((float4*)partO)[o] = oacc[i];
        partL[o] = l[i];
    }
}

// Fused epilogue: combine attn partials, y = LN(., lna); z = LN(y + res, ln)
__global__ __launch_bounds__(64) void post_kernel(const float* __restrict__ partO,
        const float* __restrict__ partL, int nsplit,
        const float* __restrict__ res,
        const float* __restrict__ lna_g, const float* __restrict__ lna_b,
        const float* __restrict__ ln_g, const float* __restrict__ ln_b,
        float* __restrict__ z) {
    int idx = blockIdx.x * 64 + threadIdx.x;         // b*S+s
    int b = idx >> 10, s = idx & 1023;
    float t[16];
    #pragma unroll
    for (int h = 0; h < HH; h++) {
        int bh = b * HH + h;
        float ox = 0.f, oy = 0.f, oz = 0.f, ow = 0.f, l = 0.f;
        for (int c = 0; c < nsplit; c++) {
            size_t o = (size_t)(c * (BB * HH) + bh) * SS + s;
            float4 O = ((const float4*)partO)[o];
            ox += O.x; oy += O.y; oz += O.z; ow += O.w;
            l += partL[o];
        }
        float rl = 1.f / l;
        t[h*4+0] = ox * rl; t[h*4+1] = oy * rl;
        t[h*4+2] = oz * rl; t[h*4+3] = ow * rl;
    }
    float mu = 0.f;
    #pragma unroll
    for (int e = 0; e < 16; e++) mu += t[e];
    mu *= (1.f / 16.f);
    float var = 0.f;
    #pragma unroll
    for (int e = 0; e < 16; e++) { float d = t[e] - mu; var += d * d; }
    var *= (1.f / 16.f);
    float r = rsqrtf(var + 1e-5f);
    if (res) {
        const float4* rp = (const float4*)(res + (size_t)idx * 16);
        #pragma unroll
        for (int i = 0; i < 4; i++) {
            float4 a = rp[i];
            t[4*i+0] = (t[4*i+0]-mu)*r*lna_g[4*i+0] + lna_b[4*i+0] + a.x;
            t[4*i+1] = (t[4*i+1]-mu)*r*lna_g[4*i+1] + lna_b[4*i+1] + a.y;
            t[4*i+2] = (t[4*i+2]-mu)*r*lna_g[4*i+2] + lna_b[4*i+2] + a.z;
            t[4*i+3] = (t[4*i+3]-mu)*r*lna_g[4*i+3] + lna_b[4*i+3] + a.w;
        }
    } else {
        #pragma unroll
        for (int e = 0; e < 16; e++) t[e] = (t[e]-mu)*r*lna_g[e] + lna_b[e];
    }
    float mu2 = 0.f;
    #pragma unroll
    for (int e = 0; e < 16; e++) mu2 += t[e];
    mu2 *= (1.f / 16.f);
    float var2 = 0.f;
    #pragma unroll
    for (int e = 0; e < 16; e++) { float d = t[e] - mu2; var2 += d * d; }
    var2 *= (1.f / 16.f);
    float r2 = rsqrtf(var2 + 1e-5f);
    float4* zp = (float4*)(z + (size_t)idx * 16);
    #pragma unroll
    for (int i = 0; i < 4; i++) {
        float4 o;
        o.x = (t[4*i+0]-mu2)*r2*ln_g[4*i+0] + ln_b[4*i+0];
        o.y = (t[4*i+1]-mu2)*r2*ln_g[4*i+1] + ln_b[4*i+1];
        o.z = (t[4*i+2]-mu2)*r2*ln_g[4*i+2] + ln_b[4*i+2];
        o.w = (t[4*i+3]-mu2)*r2*ln_g[4*i+3] + ln_b[4*i+3];
        zp[i] = o;
    }
}

// Global-average-pool over S + final linear [16 -> 10]
__global__ __launch_bounds__(256) void pool_kernel(const float* __restrict__ z2,
        const float* __restrict__ ow, const float* __restrict__ ob,
        float* __restrict__ out) {
    __shared__ float red[256 * 16];
    int b = blockIdx.x, tid = threadIdx.x;
    float acc[16];
    #pragma unroll
    for (int e = 0; e < 16; e++) acc[e] = 0.f;
    for (int s = tid; s < SS; s += 256) {
        const float4* zp = (const float4*)(z2 + ((size_t)(b * SS + s)) * 16);
        #pragma unroll
        for (int i = 0; i < 4; i++) {
            float4 a = zp[i];
            acc[4*i+0] += a.x; acc[4*i+1] += a.y;
            acc[4*i+2] += a.z; acc[4*i+3] += a.w;
        }
    }
    #pragma unroll
    for (int e = 0; e < 16; e++) red[tid * 16 + e] = acc[e];
    __syncthreads();
    for (int off = 128; off > 0; off >>= 1) {
        if (tid < off) {
            #pragma unroll
            for (int e = 0; e < 16; e++) red[tid * 16 + e] += red[(tid + off) * 16 + e];
        }
        __syncthreads();
    }
    if (tid < NCC) {
        float a = ob[tid];
        #pragma unroll
        for (int e = 0; e < 16; e++) a += (red[e] * (1.f / 1024.f)) * ow[tid * 16 + e];
        out[b * NCC + tid] = a;
    }
}

extern "C" void kernel_launch(void* const* d_in, const int* in_sizes, int n_in,
                              void* d_out, int out_size, void* d_ws, size_t ws_size,
                              hipStream_t stream) {
    const float* x       = (const float*)d_in[0];
    const float* patch_w = (const float*)d_in[1];
    const float* patch_b = (const float*)d_in[2];
    const float* bn1_g   = (const float*)d_in[3];
    const float* bn1_b   = (const float*)d_in[4];
    const float* emb_w   = (const float*)d_in[5];
    const float* emb_b   = (const float*)d_in[6];
    const float* bn2_g   = (const float*)d_in[7];
    const float* bn2_b   = (const float*)d_in[8];
    const float* dw_w    = (const float*)d_in[9];
    const float* pw_w    = (const float*)d_in[10];
    const float* bn3_g   = (const float*)d_in[11];
    const float* bn3_b   = (const float*)d_in[12];
    const float* q1_w    = (const float*)d_in[13];
    const float* k1_w    = (const float*)d_in[14];
    const float* v1_w    = (const float*)d_in[15];
    const float* lna1_g  = (const float*)d_in[16];
    const float* lna1_b  = (const float*)d_in[17];
    const float* ln1_g   = (const float*)d_in[18];
    const float* ln1_b   = (const float*)d_in[19];
    const float* q2_w    = (const float*)d_in[20];
    const float* k2_w    = (const float*)d_in[21];
    const float* v2_w    = (const float*)d_in[22];
    const float* lna2_g  = (const float*)d_in[23];
    const float* lna2_b  = (const float*)d_in[24];
    const float* ln2_g   = (const float*)d_in[25];
    const float* ln2_b   = (const float*)d_in[26];
    const float* out_w   = (const float*)d_in[27];
    const float* out_b   = (const float*)d_in[28];

    float* ws    = (float*)d_ws;
    float* pe    = ws + OFF_PE;
    float* h1    = ws + OFF_H1;
    float* h2    = ws + OFF_H2;
    float* xsrc  = ws + OFF_XSRC;
    float* gdw   = ws + OFF_Q;      // temp; dead once qkv writes q
    float* q     = ws + OFF_Q;
    float* k     = ws + OFF_K;
    float* v     = ws + OFF_V;
    float* z     = ws + OFF_Z;
    float* z2    = ws + OFF_Z2;
    float* out   = (float*)d_out;

    // attn split: 8-way (1024 blocks = 4/CU with query tiling) if ws allows,
    // else 4-way, else 2-way overlaying dead H1/H2.
    int tsplit; float *partO, *partL;
    size_t need8 = (size_t)(OFF_END + 8 * 131072 * 4 + 8 * 131072) * 4;
    size_t need4 = (size_t)(OFF_END + 4 * 131072 * 4 + 4 * 131072) * 4;
    if (ws_size >= need8) {
        tsplit = 8;
        partO = ws + OFF_END;
        partL = ws + OFF_END + 8 * 131072 * 4;
    } else if (ws_size >= need4) {
        tsplit = 4;
        partO = ws + OFF_END;
        partL = ws + OFF_END + 4 * 131072 * 4;
    } else {
        tsplit = 2;
        partO = ws + OFF_H1;
        partL = ws + OFF_H1 + 1048576;
    }

    pe_kernel<<<64, 256, 0, stream>>>(pe);
    conv1_kernel<<<1024, 256, 0, stream>>>(x, patch_w, patch_b, bn1_g, bn1_b, h1);
    conv2_kernel<<<dim3(4, 32, BB), 256, 0, stream>>>(h1, emb_w, emb_b, bn2_g, bn2_b, h2);
    dw_kernel<<<dim3(4, 16, BB), 256, 0, stream>>>(h2, dw_w, gdw);
    pw_kernel<<<512, 64, 0, stream>>>(gdw, pw_w, bn3_g, bn3_b, xsrc);

    dim3 agrid(BB * HH, tsplit);

    // layer 1
    qkv_kernel<<<dim3(512, 3), 64, 0, stream>>>(xsrc, pe, q1_w, k1_w, v1_w, q, k, v);
    if (tsplit == 8)      attn_kernel<128><<<agrid, 256, 0, stream>>>(q, k, v, partO, partL);
    else if (tsplit == 4) attn_kernel<256><<<agrid, 256, 0, stream>>>(q, k, v, partO, partL);
    else                  attn_kernel<512><<<agrid, 256, 0, stream>>>(q, k, v, partO, partL);
    post_kernel<<<512, 64, 0, stream>>>(partO, partL, tsplit, xsrc, lna1_g, lna1_b, ln1_g, ln1_b, z);

    // layer 2
    qkv_kernel<<<dim3(512, 3), 64, 0, stream>>>(z, pe, q2_w, k2_w, v2_w, q, k, v);
    if (tsplit == 8)      attn_kernel<128><<<agrid, 256, 0, stream>>>(q, k, v, partO, partL);
    else if (tsplit == 4) attn_kernel<256><<<agrid, 256, 0, stream>>>(q, k, v, partO, partL);
    else                  attn_kernel<512><<<agrid, 256, 0, stream>>>(q, k, v, partO, partL);
    post_kernel<<<512, 64, 0, stream>>>(partO, partL, tsplit, nullptr, lna2_g, lna2_b, ln2_g, ln2_b, z2);

    pool_kernel<<<BB, 256, 0, stream>>>(z2, out_w, out_b, out);
}

// Round 6
// 293.379 us; speedup vs baseline: 1.1238x; 1.1238x over previous
//
#include <hip/hip_runtime.h>
#include <hip/hip_bf16.h>
#include <math.h>

// Problem constants
#define BB 32
#define LL 4100
#define SS 1024
#define EE 16
#define HH 4
#define DHD 4
#define NCC 10

// Native exp2: single v_exp_f32 (1 ULP), vs libm exp2f -> OCML precise (~30 insts).
#define EXP2(x) __builtin_amdgcn_exp2f(x)

// Workspace layout (in floats)
#define OFF_PE   0                       // S*E = 16384
#define OFF_H1   16384                   // B*8*S = 262144
#define OFF_H2   (OFF_H1 + 262144)       // B*32*S = 1048576
#define OFF_XSRC (OFF_H2 + 1048576)      // B*S*E = 524288
#define OFF_Q    (OFF_XSRC + 524288)     // B*H*S*DH = 524288 (also gdw temp before qkv)
#define OFF_K    (OFF_Q + 524288)
#define OFF_V    (OFF_K + 524288)
#define OFF_Z    (OFF_V + 524288)        // layer-1 output
#define OFF_END  (OFF_Z + 524288)        // 3,948,544 floats = 15.8 MB
#define OFF_Z2   OFF_XSRC                // reuse xsrc for final z2 (xsrc dead after post1)

__global__ __launch_bounds__(256) void pe_kernel(float* pe) {
    int idx = blockIdx.x * 256 + threadIdx.x;       // S*E = 16384
    int s = idx >> 4, e = idx & 15;
    int j = e >> 1;
    float div = EXP2((float)j * -1.66096404744f);   // 10000^(-j/8)
    float ang = (float)s * div * (16.f / 1024.f);
    pe[idx] = (e & 1) ? cosf(ang) : sinf(ang);
}

__global__ __launch_bounds__(256) void conv1_kernel(const float* __restrict__ x,
        const float* __restrict__ w, const float* __restrict__ bias,
        const float* __restrict__ g, const float* __restrict__ bb,
        float* __restrict__ h1) {
    int idx = blockIdx.x * 256 + threadIdx.x;       // B*8*S
    int s = idx & 1023; int c = (idx >> 10) & 7; int b = idx >> 13;
    const float* xp = x + b * LL + 4 * s;
    float acc = bias[c];
    #pragma unroll
    for (int k = 0; k < 8; k++) acc += xp[k] * w[c * 8 + k];
    float inv = rsqrtf(1.f + 1e-5f);
    float v = acc * inv * g[c] + bb[c];
    h1[idx] = fmaxf(v, 0.f);
}

__global__ __launch_bounds__(256) void conv2_kernel(const float* __restrict__ h1,
        const float* __restrict__ w, const float* __restrict__ bias,
        const float* __restrict__ g, const float* __restrict__ bb,
        float* __restrict__ h2) {
    int s = blockIdx.x * 256 + threadIdx.x;
    int o = blockIdx.y, b = blockIdx.z;
    const float* hp = h1 + b * 8 * SS;
    float acc = bias[o];
    #pragma unroll
    for (int i = 0; i < 8; i++) {
        const float* row = hp + i * SS;
        const float* wr = w + (o * 8 + i) * 8;
        #pragma unroll
        for (int k = 0; k < 8; k++) {
            int t = s - 3 + k;
            if (t >= 0 && t < SS) acc += row[t] * wr[k];
        }
    }
    float inv = rsqrtf(1.f + 1e-5f);
    float v = acc * inv * g[o] + bb[o];
    h2[(b * 32 + o) * SS + s] = fmaxf(v, 0.f);
}

// Depthwise grouped conv (32->16, k=32, groups=16): thread = (b, o, s).
__global__ __launch_bounds__(256) void dw_kernel(const float* __restrict__ h2,
        const float* __restrict__ dw, float* __restrict__ gdw) {
    int s = blockIdx.x * 256 + threadIdx.x;
    int o = blockIdx.y, b = blockIdx.z;
    const float* r0 = h2 + (size_t)(b * 32 + 2 * o) * SS;
    const float* r1 = r0 + SS;
    const float* w0 = dw + (o * 2) * 32;   // uniform -> scalar loads
    const float* w1 = w0 + 32;
    float acc = 0.f;
    #pragma unroll
    for (int kk = 0; kk < 32; kk++) {
        int t = s - 15 + kk;
        if (t >= 0 && t < SS) acc += r0[t] * w0[kk] + r1[t] * w1[kk];
    }
    gdw[(size_t)(b * 16 + o) * SS + s] = acc;
}

// Pointwise 1x1 conv (16->16) + BN + ReLU, output pre-transposed [B,S,16]
__global__ __launch_bounds__(64) void pw_kernel(const float* __restrict__ gdw,
        const float* __restrict__ pw, const float* __restrict__ g,
        const float* __restrict__ bb, float* __restrict__ xsrc) {
    __shared__ float spw[256];
    int tid = threadIdx.x;
    for (int i = tid; i < 256; i += 64) spw[i] = pw[i];
    __syncthreads();
    int idx = blockIdx.x * 64 + tid;                // b*S + s
    int s = idx & 1023, b = idx >> 10;
    float gout[16];
    #pragma unroll
    for (int o = 0; o < 16; o++) gout[o] = gdw[(size_t)(b * 16 + o) * SS + s];
    float inv = rsqrtf(1.f + 1e-5f);
    float* xp = xsrc + (size_t)idx * 16;
    #pragma unroll
    for (int p = 0; p < 16; p++) {
        float acc = 0.f;
        #pragma unroll
        for (int o = 0; o < 16; o++) acc += spw[p * 16 + o] * gout[o];
        float v = acc * inv * g[p] + bb[p];
        xp[p] = fmaxf(v, 0.f);
    }
}

// QKV projection, split 3-way by blockIdx.y (0=Q,1=K,2=V).
// t = xin[b,s,:] + pe[s,:];  out[e] = sum_f W[e,f]*t[f]
// Output layout: [B,H,S,DH] for contiguous float4 reads in attention.
__global__ __launch_bounds__(64) void qkv_kernel(const float* __restrict__ xin,
        const float* __restrict__ pe,
        const float* __restrict__ wq, const float* __restrict__ wk,
        const float* __restrict__ wv,
        float* __restrict__ q, float* __restrict__ k, float* __restrict__ v) {
    __shared__ float sw[256];
    int tid = threadIdx.x;
    int which = blockIdx.y;
    const float* wsel = (which == 0) ? wq : (which == 1) ? wk : wv;
    float* osel = (which == 0) ? q : (which == 1) ? k : v;
    for (int i = tid; i < 256; i += 64) sw[i] = wsel[i];
    __syncthreads();
    int idx = blockIdx.x * 64 + tid;                // b*S + s
    int s = idx & 1023; int b = idx >> 10;
    float t[16];
    const float4* xp4 = (const float4*)(xin + (size_t)idx * 16);
    const float4* pp4 = (const float4*)(pe + s * 16);
    #pragma unroll
    for (int i = 0; i < 4; i++) {
        float4 a = xp4[i], p = pp4[i];
        t[4*i+0] = a.x + p.x; t[4*i+1] = a.y + p.y;
        t[4*i+2] = a.z + p.z; t[4*i+3] = a.w + p.w;
    }
    #pragma unroll
    for (int e = 0; e < 16; e++) {
        float acc = 0.f;
        #pragma unroll
        for (int f = 0; f < 16; f++) acc += sw[e * 16 + f] * t[f];
        int h = e >> 2, d = e & 3;
        osel[((size_t)(b * HH + h) * SS + s) * DHD + d] = acc;
    }
}

// Attention core, single-pass no-max softmax, t-split + 2-way query tiling.
// NQ=2: each thread handles queries {base+tid, base+tid+256}; K/V LDS reads
// amortized over 2 scores; grid (128 bh, 2 s-halves, tsplit) keeps 8 blocks/CU.
// Native exp2 (v_exp_f32): scores are O(1) so no-max softmax is fp32-safe.
template <int TCHUNK>
__global__ __launch_bounds__(256) void attn_kernel(const float* __restrict__ q,
        const float* __restrict__ k, const float* __restrict__ v,
        float* __restrict__ partO, float* __restrict__ partL) {
    __shared__ float4 Ks[TCHUNK], Vs[TCHUNK];
    int bh = blockIdx.x;                             // b*H + h
    int sc_ = blockIdx.y;                            // s-half (0/1)
    int tc = blockIdx.z;                             // t-chunk
    int tid = threadIdx.x;
    int t0 = tc * TCHUNK;
    const float4* kp = (const float4*)(k + (size_t)bh * SS * DHD) + t0;
    const float4* vp = (const float4*)(v + (size_t)bh * SS * DHD) + t0;
    for (int t = tid; t < TCHUNK; t += 256) { Ks[t] = kp[t]; Vs[t] = vp[t]; }
    __syncthreads();
    const float4* qp = (const float4*)(q + (size_t)bh * SS * DHD);
    // fold scale * 1/n * log2(e) into q so inner loop is: p = exp2((q.k) * |t-s|)
    const float cs = (0.25f / 1024.f) * 1.44269504089f;
    float4 qv[2]; float tf[2], l[2]; float4 oacc[2];
    #pragma unroll
    for (int i = 0; i < 2; i++) {
        int s = sc_ * 512 + tid + 256 * i;
        float4 qq = qp[s];
        qv[i] = make_float4(qq.x * cs, qq.y * cs, qq.z * cs, qq.w * cs);
        tf[i] = (float)(t0 - s);
        l[i] = 0.f;
        oacc[i] = make_float4(0.f, 0.f, 0.f, 0.f);
    }
    #pragma unroll 4
    for (int t = 0; t < TCHUNK; t++) {
        float4 kk = Ks[t];
        float4 vv = Vs[t];
        #pragma unroll
        for (int i = 0; i < 2; i++) {
            float d = qv[i].x*kk.x + qv[i].y*kk.y + qv[i].z*kk.z + qv[i].w*kk.w;
            float p = EXP2(d * fabsf(tf[i]));
            tf[i] += 1.f;
            l[i] += p;
            oacc[i].x += p*vv.x; oacc[i].y += p*vv.y;
            oacc[i].z += p*vv.z; oacc[i].w += p*vv.w;
        }
    }
    #pragma unroll
    for (int i = 0; i < 2; i++) {
        int s = sc_ * 512 + tid + 256 * i;
        size_t o = (size_t)(tc * (BB * HH) + bh) * SS + s;
        ((float4*)partO)[o] = oacc[i];
        partL[o] = l[i];
    }
}

// Fused epilogue: combine attn partials, y = LN(., lna); z = LN(y + res, ln)
__global__ __launch_bounds__(64) void post_kernel(const float* __restrict__ partO,
        const float* __restrict__ partL, int nsplit,
        const float* __restrict__ res,
        const float* __restrict__ lna_g, const float* __restrict__ lna_b,
        const float* __restrict__ ln_g, const float* __restrict__ ln_b,
        float* __restrict__ z) {
    int idx = blockIdx.x * 64 + threadIdx.x;         // b*S+s
    int b = idx >> 10, s = idx & 1023;
    float t[16];
    #pragma unroll
    for (int h = 0; h < HH; h++) {
        int bh = b * HH + h;
        float ox = 0.f, oy = 0.f, oz = 0.f, ow = 0.f, l = 0.f;
        for (int c = 0; c < nsplit; c++) {
            size_t o = (size_t)(c * (BB * HH) + bh) * SS + s;
            float4 O = ((const float4*)partO)[o];
            ox += O.x; oy += O.y; oz += O.z; ow += O.w;
            l += partL[o];
        }
        float rl = 1.f / l;
        t[h*4+0] = ox * rl; t[h*4+1] = oy * rl;
        t[h*4+2] = oz * rl; t[h*4+3] = ow * rl;
    }
    float mu = 0.f;
    #pragma unroll
    for (int e = 0; e < 16; e++) mu += t[e];
    mu *= (1.f / 16.f);
    float var = 0.f;
    #pragma unroll
    for (int e = 0; e < 16; e++) { float d = t[e] - mu; var += d * d; }
    var *= (1.f / 16.f);
    float r = rsqrtf(var + 1e-5f);
    if (res) {
        const float4* rp = (const float4*)(res + (size_t)idx * 16);
        #pragma unroll
        for (int i = 0; i < 4; i++) {
            float4 a = rp[i];
            t[4*i+0] = (t[4*i+0]-mu)*r*lna_g[4*i+0] + lna_b[4*i+0] + a.x;
            t[4*i+1] = (t[4*i+1]-mu)*r*lna_g[4*i+1] + lna_b[4*i+1] + a.y;
            t[4*i+2] = (t[4*i+2]-mu)*r*lna_g[4*i+2] + lna_b[4*i+2] + a.z;
            t[4*i+3] = (t[4*i+3]-mu)*r*lna_g[4*i+3] + lna_b[4*i+3] + a.w;
        }
    } else {
        #pragma unroll
        for (int e = 0; e < 16; e++) t[e] = (t[e]-mu)*r*lna_g[e] + lna_b[e];
    }
    float mu2 = 0.f;
    #pragma unroll
    for (int e = 0; e < 16; e++) mu2 += t[e];
    mu2 *= (1.f / 16.f);
    float var2 = 0.f;
    #pragma unroll
    for (int e = 0; e < 16; e++) { float d = t[e] - mu2; var2 += d * d; }
    var2 *= (1.f / 16.f);
    float r2 = rsqrtf(var2 + 1e-5f);
    float4* zp = (float4*)(z + (size_t)idx * 16);
    #pragma unroll
    for (int i = 0; i < 4; i++) {
        float4 o;
        o.x = (t[4*i+0]-mu2)*r2*ln_g[4*i+0] + ln_b[4*i+0];
        o.y = (t[4*i+1]-mu2)*r2*ln_g[4*i+1] + ln_b[4*i+1];
        o.z = (t[4*i+2]-mu2)*r2*ln_g[4*i+2] + ln_b[4*i+2];
        o.w = (t[4*i+3]-mu2)*r2*ln_g[4*i+3] + ln_b[4*i+3];
        zp[i] = o;
    }
}

// Global-average-pool over S + final linear [16 -> 10]
__global__ __launch_bounds__(256) void pool_kernel(const float* __restrict__ z2,
        const float* __restrict__ ow, const float* __restrict__ ob,
        float* __restrict__ out) {
    __shared__ float red[256 * 16];
    int b = blockIdx.x, tid = threadIdx.x;
    float acc[16];
    #pragma unroll
    for (int e = 0; e < 16; e++) acc[e] = 0.f;
    for (int s = tid; s < SS; s += 256) {
        const float4* zp = (const float4*)(z2 + ((size_t)(b * SS + s)) * 16);
        #pragma unroll
        for (int i = 0; i < 4; i++) {
            float4 a = zp[i];
            acc[4*i+0] += a.x; acc[4*i+1] += a.y;
            acc[4*i+2] += a.z; acc[4*i+3] += a.w;
        }
    }
    #pragma unroll
    for (int e = 0; e < 16; e++) red[tid * 16 + e] = acc[e];
    __syncthreads();
    for (int off = 128; off > 0; off >>= 1) {
        if (tid < off) {
            #pragma unroll
            for (int e = 0; e < 16; e++) red[tid * 16 + e] += red[(tid + off) * 16 + e];
        }
        __syncthreads();
    }
    if (tid < NCC) {
        float a = ob[tid];
        #pragma unroll
        for (int e = 0; e < 16; e++) a += (red[e] * (1.f / 1024.f)) * ow[tid * 16 + e];
        out[b * NCC + tid] = a;
    }
}

extern "C" void kernel_launch(void* const* d_in, const int* in_sizes, int n_in,
                              void* d_out, int out_size, void* d_ws, size_t ws_size,
                              hipStream_t stream) {
    const float* x       = (const float*)d_in[0];
    const float* patch_w = (const float*)d_in[1];
    const float* patch_b = (const float*)d_in[2];
    const float* bn1_g   = (const float*)d_in[3];
    const float* bn1_b   = (const float*)d_in[4];
    const float* emb_w   = (const float*)d_in[5];
    const float* emb_b   = (const float*)d_in[6];
    const float* bn2_g   = (const float*)d_in[7];
    const float* bn2_b   = (const float*)d_in[8];
    const float* dw_w    = (const float*)d_in[9];
    const float* pw_w    = (const float*)d_in[10];
    const float* bn3_g   = (const float*)d_in[11];
    const float* bn3_b   = (const float*)d_in[12];
    const float* q1_w    = (const float*)d_in[13];
    const float* k1_w    = (const float*)d_in[14];
    const float* v1_w    = (const float*)d_in[15];
    const float* lna1_g  = (const float*)d_in[16];
    const float* lna1_b  = (const float*)d_in[17];
    const float* ln1_g   = (const float*)d_in[18];
    const float* ln1_b   = (const float*)d_in[19];
    const float* q2_w    = (const float*)d_in[20];
    const float* k2_w    = (const float*)d_in[21];
    const float* v2_w    = (const float*)d_in[22];
    const float* lna2_g  = (const float*)d_in[23];
    const float* lna2_b  = (const float*)d_in[24];
    const float* ln2_g   = (const float*)d_in[25];
    const float* ln2_b   = (const float*)d_in[26];
    const float* out_w   = (const float*)d_in[27];
    const float* out_b   = (const float*)d_in[28];

    float* ws    = (float*)d_ws;
    float* pe    = ws + OFF_PE;
    float* h1    = ws + OFF_H1;
    float* h2    = ws + OFF_H2;
    float* xsrc  = ws + OFF_XSRC;
    float* gdw   = ws + OFF_Q;      // temp; dead once qkv writes q
    float* q     = ws + OFF_Q;
    float* k     = ws + OFF_K;
    float* v     = ws + OFF_V;
    float* z     = ws + OFF_Z;
    float* z2    = ws + OFF_Z2;
    float* out   = (float*)d_out;

    // attn split: 8-way (2048 blocks = 8/CU with NQ=2 query tiling) if ws allows,
    // else 4-way, else 2-way overlaying dead H1/H2.
    int tsplit; float *partO, *partL;
    size_t need8 = (size_t)(OFF_END + 8 * 131072 * 4 + 8 * 131072) * 4;
    size_t need4 = (size_t)(OFF_END + 4 * 131072 * 4 + 4 * 131072) * 4;
    if (ws_size >= need8) {
        tsplit = 8;
        partO = ws + OFF_END;
        partL = ws + OFF_END + 8 * 131072 * 4;
    } else if (ws_size >= need4) {
        tsplit = 4;
        partO = ws + OFF_END;
        partL = ws + OFF_END + 4 * 131072 * 4;
    } else {
        tsplit = 2;
        partO = ws + OFF_H1;
        partL = ws + OFF_H1 + 1048576;
    }

    pe_kernel<<<64, 256, 0, stream>>>(pe);
    conv1_kernel<<<1024, 256, 0, stream>>>(x, patch_w, patch_b, bn1_g, bn1_b, h1);
    conv2_kernel<<<dim3(4, 32, BB), 256, 0, stream>>>(h1, emb_w, emb_b, bn2_g, bn2_b, h2);
    dw_kernel<<<dim3(4, 16, BB), 256, 0, stream>>>(h2, dw_w, gdw);
    pw_kernel<<<512, 64, 0, stream>>>(gdw, pw_w, bn3_g, bn3_b, xsrc);

    dim3 agrid(BB * HH, 2, tsplit);

    // layer 1
    qkv_kernel<<<dim3(512, 3), 64, 0, stream>>>(xsrc, pe, q1_w, k1_w, v1_w, q, k, v);
    if (tsplit == 8)      attn_kernel<128><<<agrid, 256, 0, stream>>>(q, k, v, partO, partL);
    else if (tsplit == 4) attn_kernel<256><<<agrid, 256, 0, stream>>>(q, k, v, partO, partL);
    else                  attn_kernel<512><<<agrid, 256, 0, stream>>>(q, k, v, partO, partL);
    post_kernel<<<512, 64, 0, stream>>>(partO, partL, tsplit, xsrc, lna1_g, lna1_b, ln1_g, ln1_b, z);

    // layer 2
    qkv_kernel<<<dim3(512, 3), 64, 0, stream>>>(z, pe, q2_w, k2_w, v2_w, q, k, v);
    if (tsplit == 8)      attn_kernel<128><<<agrid, 256, 0, stream>>>(q, k, v, partO, partL);
    else if (tsplit == 4) attn_kernel<256><<<agrid, 256, 0, stream>>>(q, k, v, partO, partL);
    else                  attn_kernel<512><<<agrid, 256, 0, stream>>>(q, k, v, partO, partL);
    post_kernel<<<512, 64, 0, stream>>>(partO, partL, tsplit, nullptr, lna2_g, lna2_b, ln2_g, ln2_b, z2);

    pool_kernel<<<BB, 256, 0, stream>>>(z2, out_w, out_b, out);
}

// Round 7
// 289.401 us; speedup vs baseline: 1.1393x; 1.0137x over previous
//
#include <hip/hip_runtime.h>
#include <hip/hip_bf16.h>
#include <math.h>

// Problem constants
#define BB 32
#define LL 4100
#define SS 1024
#define EE 16
#define HH 4
#define DHD 4
#define NCC 10

// Native exp2: single v_exp_f32 (1 ULP), vs libm exp2f -> OCML precise (~30 insts).
#define EXP2(x) __builtin_amdgcn_exp2f(x)

// Workspace layout (in floats)
#define OFF_PE   0                       // S*E = 16384
#define OFF_H1   16384                   // B*8*S = 262144 (reused: pool partials)
#define OFF_H2   (OFF_H1 + 262144)       // B*32*S = 1048576
#define OFF_XSRC (OFF_H2 + 1048576)      // B*S*E = 524288
#define OFF_Q    (OFF_XSRC + 524288)     // B*H*S*DH = 524288 (also gdw temp before qkv)
#define OFF_K    (OFF_Q + 524288)
#define OFF_V    (OFF_K + 524288)
#define OFF_Z    (OFF_V + 524288)        // layer-1 output
#define OFF_END  (OFF_Z + 524288)        // 3,948,544 floats = 15.8 MB
#define OFF_Z2   OFF_XSRC                // reuse xsrc for final z2 (xsrc dead after post1)
#define OFF_POOLP OFF_H1                 // pool partials [B*4][16] (H1 dead; partO dead by then too)

__global__ __launch_bounds__(256) void pe_kernel(float* pe) {
    int idx = blockIdx.x * 256 + threadIdx.x;       // S*E = 16384
    int s = idx >> 4, e = idx & 15;
    int j = e >> 1;
    float div = EXP2((float)j * -1.66096404744f);   // 10000^(-j/8)
    float ang = (float)s * div * (16.f / 1024.f);
    pe[idx] = (e & 1) ? cosf(ang) : sinf(ang);
}

__global__ __launch_bounds__(256) void conv1_kernel(const float* __restrict__ x,
        const float* __restrict__ w, const float* __restrict__ bias,
        const float* __restrict__ g, const float* __restrict__ bb,
        float* __restrict__ h1) {
    int idx = blockIdx.x * 256 + threadIdx.x;       // B*8*S
    int s = idx & 1023; int c = (idx >> 10) & 7; int b = idx >> 13;
    const float* xp = x + b * LL + 4 * s;
    float acc = bias[c];
    #pragma unroll
    for (int k = 0; k < 8; k++) acc += xp[k] * w[c * 8 + k];
    float inv = rsqrtf(1.f + 1e-5f);
    float v = acc * inv * g[c] + bb[c];
    h1[idx] = fmaxf(v, 0.f);
}

__global__ __launch_bounds__(256) void conv2_kernel(const float* __restrict__ h1,
        const float* __restrict__ w, const float* __restrict__ bias,
        const float* __restrict__ g, const float* __restrict__ bb,
        float* __restrict__ h2) {
    int s = blockIdx.x * 256 + threadIdx.x;
    int o = blockIdx.y, b = blockIdx.z;
    const float* hp = h1 + b * 8 * SS;
    float acc = bias[o];
    #pragma unroll
    for (int i = 0; i < 8; i++) {
        const float* row = hp + i * SS;
        const float* wr = w + (o * 8 + i) * 8;
        #pragma unroll
        for (int k = 0; k < 8; k++) {
            int t = s - 3 + k;
            if (t >= 0 && t < SS) acc += row[t] * wr[k];
        }
    }
    float inv = rsqrtf(1.f + 1e-5f);
    float v = acc * inv * g[o] + bb[o];
    h2[(b * 32 + o) * SS + s] = fmaxf(v, 0.f);
}

// Depthwise grouped conv (32->16, k=32, groups=16): thread = (b, o, s).
__global__ __launch_bounds__(256) void dw_kernel(const float* __restrict__ h2,
        const float* __restrict__ dw, float* __restrict__ gdw) {
    int s = blockIdx.x * 256 + threadIdx.x;
    int o = blockIdx.y, b = blockIdx.z;
    const float* r0 = h2 + (size_t)(b * 32 + 2 * o) * SS;
    const float* r1 = r0 + SS;
    const float* w0 = dw + (o * 2) * 32;   // uniform -> scalar loads
    const float* w1 = w0 + 32;
    float acc = 0.f;
    #pragma unroll
    for (int kk = 0; kk < 32; kk++) {
        int t = s - 15 + kk;
        if (t >= 0 && t < SS) acc += r0[t] * w0[kk] + r1[t] * w1[kk];
    }
    gdw[(size_t)(b * 16 + o) * SS + s] = acc;
}

// Pointwise 1x1 conv (16->16) + BN + ReLU, output pre-transposed [B,S,16].
// Weights read directly from global with uniform index -> s_load (no LDS
// broadcast: uniform ds_read_b32 costs ~5.8 cyc/wave each, 256 of them).
__global__ __launch_bounds__(64) void pw_kernel(const float* __restrict__ gdw,
        const float* __restrict__ pw, const float* __restrict__ g,
        const float* __restrict__ bb, float* __restrict__ xsrc) {
    int tid = threadIdx.x;
    int idx = blockIdx.x * 64 + tid;                // b*S + s
    int s = idx & 1023, b = idx >> 10;
    float gout[16];
    #pragma unroll
    for (int o = 0; o < 16; o++) gout[o] = gdw[(size_t)(b * 16 + o) * SS + s];
    float inv = rsqrtf(1.f + 1e-5f);
    float* xp = xsrc + (size_t)idx * 16;
    #pragma unroll
    for (int p = 0; p < 16; p++) {
        float acc = 0.f;
        #pragma unroll
        for (int o = 0; o < 16; o++) acc += pw[p * 16 + o] * gout[o];
        float v = acc * inv * g[p] + bb[p];
        xp[p] = fmaxf(v, 0.f);
    }
}

// QKV projection, split 3-way by blockIdx.y (0=Q,1=K,2=V).
// Weights via uniform global reads (s_load), not LDS broadcast.
__global__ __launch_bounds__(64) void qkv_kernel(const float* __restrict__ xin,
        const float* __restrict__ pe,
        const float* __restrict__ wq, const float* __restrict__ wk,
        const float* __restrict__ wv,
        float* __restrict__ q, float* __restrict__ k, float* __restrict__ v) {
    int tid = threadIdx.x;
    int which = blockIdx.y;
    const float* wsel = (which == 0) ? wq : (which == 1) ? wk : wv;
    float* osel = (which == 0) ? q : (which == 1) ? k : v;
    int idx = blockIdx.x * 64 + tid;                // b*S + s
    int s = idx & 1023; int b = idx >> 10;
    float t[16];
    const float4* xp4 = (const float4*)(xin + (size_t)idx * 16);
    const float4* pp4 = (const float4*)(pe + s * 16);
    #pragma unroll
    for (int i = 0; i < 4; i++) {
        float4 a = xp4[i], p = pp4[i];
        t[4*i+0] = a.x + p.x; t[4*i+1] = a.y + p.y;
        t[4*i+2] = a.z + p.z; t[4*i+3] = a.w + p.w;
    }
    #pragma unroll
    for (int e = 0; e < 16; e++) {
        float acc = 0.f;
        #pragma unroll
        for (int f = 0; f < 16; f++) acc += wsel[e * 16 + f] * t[f];
        int h = e >> 2, d = e & 3;
        osel[((size_t)(b * HH + h) * SS + s) * DHD + d] = acc;
    }
}

// Attention core: single-pass no-max softmax, t-split, NQ=4 query tiling
// (amortizes the per-CU LDS broadcast pipe — R4-R6 showed it, not VALU, binds)
// with native exp2. Grid (bh, tc) = (128, tsplit); block covers all S queries.
template <int TCHUNK>
__global__ __launch_bounds__(256) void attn_kernel(const float* __restrict__ q,
        const float* __restrict__ k, const float* __restrict__ v,
        float* __restrict__ partO, float* __restrict__ partL) {
    __shared__ float4 Ks[TCHUNK], Vs[TCHUNK];
    int bh = blockIdx.x;                             // b*H + h
    int tc = blockIdx.y;                             // t-chunk
    int tid = threadIdx.x;
    int t0 = tc * TCHUNK;
    const float4* kp = (const float4*)(k + (size_t)bh * SS * DHD) + t0;
    const float4* vp = (const float4*)(v + (size_t)bh * SS * DHD) + t0;
    for (int t = tid; t < TCHUNK; t += 256) { Ks[t] = kp[t]; Vs[t] = vp[t]; }
    __syncthreads();
    const float4* qp = (const float4*)(q + (size_t)bh * SS * DHD);
    // fold scale * 1/n * log2(e) into q so inner loop is: p = exp2((q.k) * |t-s|)
    const float cs = (0.25f / 1024.f) * 1.44269504089f;
    float4 qv[4]; float tf[4], l[4]; float4 oacc[4];
    #pragma unroll
    for (int i = 0; i < 4; i++) {
        int s = tid + 256 * i;
        float4 qq = qp[s];
        qv[i] = make_float4(qq.x * cs, qq.y * cs, qq.z * cs, qq.w * cs);
        tf[i] = (float)(t0 - s);
        l[i] = 0.f;
        oacc[i] = make_float4(0.f, 0.f, 0.f, 0.f);
    }
    #pragma unroll 4
    for (int t = 0; t < TCHUNK; t++) {
        float4 kk = Ks[t];
        float4 vv = Vs[t];
        #pragma unroll
        for (int i = 0; i < 4; i++) {
            float d = qv[i].x*kk.x + qv[i].y*kk.y + qv[i].z*kk.z + qv[i].w*kk.w;
            float p = EXP2(d * fabsf(tf[i]));
            tf[i] += 1.f;
            l[i] += p;
            oacc[i].x += p*vv.x; oacc[i].y += p*vv.y;
            oacc[i].z += p*vv.z; oacc[i].w += p*vv.w;
        }
    }
    #pragma unroll
    for (int i = 0; i < 4; i++) {
        int s = tid + 256 * i;
        size_t o = (size_t)(tc * (BB * HH) + bh) * SS + s;
        ((float4*)partO)[o] = oacc[i];
        partL[o] = l[i];
    }
}

// Fused epilogue: thread-per-(b,s,h) combines partials (4x the waves of the
// old thread-per-(b,s) version), LDS handoff, then lane-per-(b,s) double-LN.
__global__ __launch_bounds__(256) void post_kernel(const float* __restrict__ partO,
        const float* __restrict__ partL, int nsplit,
        const float* __restrict__ res,
        const float* __restrict__ lna_g, const float* __restrict__ lna_b,
        const float* __restrict__ ln_g, const float* __restrict__ ln_b,
        float* __restrict__ z) {
    __shared__ float sh[64 * 17];                    // stride 17: conflict-free
    int tid = threadIdx.x;
    int lane = tid & 63;
    int h = tid >> 6;                                // 0..3
    int item = blockIdx.x * 64 + lane;               // b*S + s
    int b = item >> 10, s = item & 1023;
    int bh = b * HH + h;
    float ox = 0.f, oy = 0.f, oz = 0.f, ow = 0.f, l = 0.f;
    for (int c = 0; c < nsplit; c++) {
        size_t o = (size_t)(c * (BB * HH) + bh) * SS + s;
        float4 O = ((const float4*)partO)[o];
        ox += O.x; oy += O.y; oz += O.z; ow += O.w;
        l += partL[o];
    }
    float rl = 1.f / l;
    float* row = sh + lane * 17 + h * 4;
    row[0] = ox * rl; row[1] = oy * rl; row[2] = oz * rl; row[3] = ow * rl;
    __syncthreads();
    if (tid < 64) {
        float t[16];
        #pragma unroll
        for (int e = 0; e < 16; e++) t[e] = sh[lane * 17 + e];
        float mu = 0.f;
        #pragma unroll
        for (int e = 0; e < 16; e++) mu += t[e];
        mu *= (1.f / 16.f);
        float var = 0.f;
        #pragma unroll
        for (int e = 0; e < 16; e++) { float d = t[e] - mu; var += d * d; }
        var *= (1.f / 16.f);
        float r = rsqrtf(var + 1e-5f);
        if (res) {
            const float4* rp = (const float4*)(res + (size_t)item * 16);
            #pragma unroll
            for (int i = 0; i < 4; i++) {
                float4 a = rp[i];
                t[4*i+0] = (t[4*i+0]-mu)*r*lna_g[4*i+0] + lna_b[4*i+0] + a.x;
                t[4*i+1] = (t[4*i+1]-mu)*r*lna_g[4*i+1] + lna_b[4*i+1] + a.y;
                t[4*i+2] = (t[4*i+2]-mu)*r*lna_g[4*i+2] + lna_b[4*i+2] + a.z;
                t[4*i+3] = (t[4*i+3]-mu)*r*lna_g[4*i+3] + lna_b[4*i+3] + a.w;
            }
        } else {
            #pragma unroll
            for (int e = 0; e < 16; e++) t[e] = (t[e]-mu)*r*lna_g[e] + lna_b[e];
        }
        float mu2 = 0.f;
        #pragma unroll
        for (int e = 0; e < 16; e++) mu2 += t[e];
        mu2 *= (1.f / 16.f);
        float var2 = 0.f;
        #pragma unroll
        for (int e = 0; e < 16; e++) { float d = t[e] - mu2; var2 += d * d; }
        var2 *= (1.f / 16.f);
        float r2 = rsqrtf(var2 + 1e-5f);
        float4* zp = (float4*)(z + (size_t)item * 16);
        #pragma unroll
        for (int i = 0; i < 4; i++) {
            float4 o;
            o.x = (t[4*i+0]-mu2)*r2*ln_g[4*i+0] + ln_b[4*i+0];
            o.y = (t[4*i+1]-mu2)*r2*ln_g[4*i+1] + ln_b[4*i+1];
            o.z = (t[4*i+2]-mu2)*r2*ln_g[4*i+2] + ln_b[4*i+2];
            o.w = (t[4*i+3]-mu2)*r2*ln_g[4*i+3] + ln_b[4*i+3];
            zp[i] = o;
        }
    }
}

// Pool stage 1: block per (b, s-quarter); partial sums [B*4][16]
__global__ __launch_bounds__(256) void pool1_kernel(const float* __restrict__ z2,
        float* __restrict__ part) {
    __shared__ float red[256 * 17];
    int b = blockIdx.x, qd = blockIdx.y, tid = threadIdx.x;
    int s = qd * 256 + tid;
    const float4* zp = (const float4*)(z2 + ((size_t)(b * SS + s)) * 16);
    #pragma unroll
    for (int i = 0; i < 4; i++) {
        float4 a = zp[i];
        red[tid * 17 + 4*i+0] = a.x; red[tid * 17 + 4*i+1] = a.y;
        red[tid * 17 + 4*i+2] = a.z; red[tid * 17 + 4*i+3] = a.w;
    }
    __syncthreads();
    for (int off = 128; off > 0; off >>= 1) {
        if (tid < off) {
            #pragma unroll
            for (int e = 0; e < 16; e++) red[tid * 17 + e] += red[(tid + off) * 17 + e];
        }
        __syncthreads();
    }
    if (tid < 16) part[(b * 4 + qd) * 16 + tid] = red[tid];
}

// Pool stage 2: combine quarters + final linear [16 -> 10]
__global__ __launch_bounds__(512) void pool2_kernel(const float* __restrict__ part,
        const float* __restrict__ ow, const float* __restrict__ ob,
        float* __restrict__ out) {
    int t = threadIdx.x;
    if (t < BB * NCC) {
        int b = t / NCC, c = t - b * NCC;
        float a = ob[c];
        #pragma unroll
        for (int e = 0; e < 16; e++) {
            float sum = part[(b*4+0)*16+e] + part[(b*4+1)*16+e]
                      + part[(b*4+2)*16+e] + part[(b*4+3)*16+e];
            a += (sum * (1.f / 1024.f)) * ow[c * 16 + e];
        }
        out[b * NCC + c] = a;
    }
}

extern "C" void kernel_launch(void* const* d_in, const int* in_sizes, int n_in,
                              void* d_out, int out_size, void* d_ws, size_t ws_size,
                              hipStream_t stream) {
    const float* x       = (const float*)d_in[0];
    const float* patch_w = (const float*)d_in[1];
    const float* patch_b = (const float*)d_in[2];
    const float* bn1_g   = (const float*)d_in[3];
    const float* bn1_b   = (const float*)d_in[4];
    const float* emb_w   = (const float*)d_in[5];
    const float* emb_b   = (const float*)d_in[6];
    const float* bn2_g   = (const float*)d_in[7];
    const float* bn2_b   = (const float*)d_in[8];
    const float* dw_w    = (const float*)d_in[9];
    const float* pw_w    = (const float*)d_in[10];
    const float* bn3_g   = (const float*)d_in[11];
    const float* bn3_b   = (const float*)d_in[12];
    const float* q1_w    = (const float*)d_in[13];
    const float* k1_w    = (const float*)d_in[14];
    const float* v1_w    = (const float*)d_in[15];
    const float* lna1_g  = (const float*)d_in[16];
    const float* lna1_b  = (const float*)d_in[17];
    const float* ln1_g   = (const float*)d_in[18];
    const float* ln1_b   = (const float*)d_in[19];
    const float* q2_w    = (const float*)d_in[20];
    const float* k2_w    = (const float*)d_in[21];
    const float* v2_w    = (const float*)d_in[22];
    const float* lna2_g  = (const float*)d_in[23];
    const float* lna2_b  = (const float*)d_in[24];
    const float* ln2_g   = (const float*)d_in[25];
    const float* ln2_b   = (const float*)d_in[26];
    const float* out_w   = (const float*)d_in[27];
    const float* out_b   = (const float*)d_in[28];

    float* ws    = (float*)d_ws;
    float* pe    = ws + OFF_PE;
    float* h1    = ws + OFF_H1;
    float* h2    = ws + OFF_H2;
    float* xsrc  = ws + OFF_XSRC;
    float* gdw   = ws + OFF_Q;      // temp; dead once qkv writes q
    float* q     = ws + OFF_Q;
    float* k     = ws + OFF_K;
    float* v     = ws + OFF_V;
    float* z     = ws + OFF_Z;
    float* z2    = ws + OFF_Z2;
    float* poolp = ws + OFF_POOLP;
    float* out   = (float*)d_out;

    // attn t-split: 8-way if workspace allows, else 4-way, else 2-way (overlay).
    int tsplit; float *partO, *partL;
    size_t need8 = (size_t)(OFF_END + 8 * 131072 * 4 + 8 * 131072) * 4;
    size_t need4 = (size_t)(OFF_END + 4 * 131072 * 4 + 4 * 131072) * 4;
    if (ws_size >= need8) {
        tsplit = 8;
        partO = ws + OFF_END;
        partL = ws + OFF_END + 8 * 131072 * 4;
    } else if (ws_size >= need4) {
        tsplit = 4;
        partO = ws + OFF_END;
        partL = ws + OFF_END + 4 * 131072 * 4;
    } else {
        tsplit = 2;
        partO = ws + OFF_H1;
        partL = ws + OFF_H1 + 1048576;
    }

    pe_kernel<<<64, 256, 0, stream>>>(pe);
    conv1_kernel<<<1024, 256, 0, stream>>>(x, patch_w, patch_b, bn1_g, bn1_b, h1);
    conv2_kernel<<<dim3(4, 32, BB), 256, 0, stream>>>(h1, emb_w, emb_b, bn2_g, bn2_b, h2);
    dw_kernel<<<dim3(4, 16, BB), 256, 0, stream>>>(h2, dw_w, gdw);
    pw_kernel<<<512, 64, 0, stream>>>(gdw, pw_w, bn3_g, bn3_b, xsrc);

    dim3 agrid(BB * HH, tsplit);

    // layer 1
    qkv_kernel<<<dim3(512, 3), 64, 0, stream>>>(xsrc, pe, q1_w, k1_w, v1_w, q, k, v);
    if (tsplit == 8)      attn_kernel<128><<<agrid, 256, 0, stream>>>(q, k, v, partO, partL);
    else if (tsplit == 4) attn_kernel<256><<<agrid, 256, 0, stream>>>(q, k, v, partO, partL);
    else                  attn_kernel<512><<<agrid, 256, 0, stream>>>(q, k, v, partO, partL);
    post_kernel<<<512, 256, 0, stream>>>(partO, partL, tsplit, xsrc, lna1_g, lna1_b, ln1_g, ln1_b, z);

    // layer 2
    qkv_kernel<<<dim3(512, 3), 64, 0, stream>>>(z, pe, q2_w, k2_w, v2_w, q, k, v);
    if (tsplit == 8)      attn_kernel<128><<<agrid, 256, 0, stream>>>(q, k, v, partO, partL);
    else if (tsplit == 4) attn_kernel<256><<<agrid, 256, 0, stream>>>(q, k, v, partO, partL);
    else                  attn_kernel<512><<<agrid, 256, 0, stream>>>(q, k, v, partO, partL);
    post_kernel<<<512, 256, 0, stream>>>(partO, partL, tsplit, nullptr, lna2_g, lna2_b, ln2_g, ln2_b, z2);

    pool1_kernel<<<dim3(BB, 4), 256, 0, stream>>>(z2, poolp);
    pool2_kernel<<<1, 512, 0, stream>>>(poolp, out_w, out_b, out);
}